// Round 6
// baseline (799.615 us; speedup 1.0000x reference)
//
#include <hip/hip_runtime.h>
#include <hip/hip_bf16.h>

#define N_REL 8

typedef unsigned short ushort_t;
typedef unsigned int uint_t;
typedef __attribute__((ext_vector_type(8))) short short8;   // bf16x8 MFMA operand
typedef __attribute__((ext_vector_type(4))) float floatx4;  // MFMA accumulator

static __device__ __forceinline__ ushort_t f2bf(float f) {
    union { float f; unsigned u; } v; v.f = f;
    unsigned r = v.u + 0x7fff + ((v.u >> 16) & 1);
    return (ushort_t)(r >> 16);
}

typedef __attribute__((address_space(1))) void glob_void;
typedef __attribute__((address_space(3))) void lds_void;

static __device__ __forceinline__ void load_lds16(const void* g, void* l) {
    __builtin_amdgcn_global_load_lds((glob_void*)g, (lds_void*)l, 16, 0, 0);
}

// Stage one 128x64 bf16 half-tile (16 KB) from global [rows][K] into LDS, linear
// [r][chunk] layout, with the st-swizzle (chunk ^= r&7) pre-applied on the GLOBAL
// source address (global_load_lds writes wave-uniform-base + lane*16 only).
static __device__ __forceinline__ void stage_half(const ushort_t* __restrict__ g,
                                                  int row0, int rmax, int K, int k0,
                                                  ushort_t* lds, int w, int l) {
    const int rl = l >> 3;
    const int gc = ((l & 7) ^ rl) * 8;  // swizzled 16B chunk within the row
#pragma unroll
    for (int s = 0; s < 2; ++s) {
        int r = row0 + s * 64 + w * 8 + rl;
        r = r < rmax ? r : rmax - 1;  // clamp (stores are guarded; dup rows harmless)
        load_lds16(g + (size_t)r * K + k0 + gc, lds + (s * 64 + w * 8) * 64);
    }
}

// ---------------- sort infrastructure ----------------

__global__ __launch_bounds__(256) void hist_kernel(const int* __restrict__ dst,
                                                   const int* __restrict__ et,
                                                   int* __restrict__ cnt, int E) {
    int e = blockIdx.x * blockDim.x + threadIdx.x;
    if (e < E) atomicAdd(&cnt[dst[e] * N_REL + et[e]], 1);
}

__global__ __launch_bounds__(256) void scan1(const int* __restrict__ cnt,
                                             int* __restrict__ off,
                                             int* __restrict__ bsum, int nk) {
    __shared__ int s[256];
    int t = threadIdx.x;
    int k = blockIdx.x * 256 + t;
    int v = k < nk ? cnt[k] : 0;
    s[t] = v; __syncthreads();
    for (int d = 1; d < 256; d <<= 1) {
        int x = (t >= d) ? s[t - d] : 0;
        __syncthreads(); s[t] += x; __syncthreads();
    }
    if (k < nk) off[k] = s[t] - v;
    if (t == 255) bsum[blockIdx.x] = s[255];
}

__global__ __launch_bounds__(1024) void scan2(int* __restrict__ bsum, int nb) {
    __shared__ int s[1024];
    int t = threadIdx.x;
    int v = t < nb ? bsum[t] : 0;
    s[t] = v; __syncthreads();
    for (int d = 1; d < 1024; d <<= 1) {
        int x = (t >= d) ? s[t - d] : 0;
        __syncthreads(); s[t] += x; __syncthreads();
    }
    if (t < nb) bsum[t] = s[t] - v;
}

__global__ __launch_bounds__(256) void scan3(int* __restrict__ off,
                                             const int* __restrict__ bsum,
                                             int* __restrict__ cursor,
                                             int nk) {
    int k = blockIdx.x * 256 + threadIdx.x;
    if (k >= nk) return;
    int o = off[k] + bsum[k >> 8];
    off[k] = o;
    cursor[k] = o;
}

// Packs everything the gather loop needs into one 8-byte descriptor per edge:
// {src | rel<<27, 1.0f/count}. cnt[] is final (hist completed) when this runs.
__global__ __launch_bounds__(256) void scatter_desc(const int* __restrict__ dst,
                                                    const int* __restrict__ et,
                                                    const int* __restrict__ src,
                                                    const int* __restrict__ cnt,
                                                    int* __restrict__ cursor,
                                                    uint2* __restrict__ edesc, int E) {
    int e = blockIdx.x * blockDim.x + threadIdx.x;
    if (e < E) {
        int key = dst[e] * N_REL + et[e];
        int pos = atomicAdd(&cursor[key], 1);
        float inv = 1.0f / (float)cnt[key];
        edesc[pos] = make_uint2((uint_t)src[e] | ((uint_t)et[e] << 27),
                                __float_as_uint(inv));
    }
}

// ---------------- casts ----------------

__global__ __launch_bounds__(256) void cast_bf16(const float* __restrict__ in,
                                                 ushort_t* __restrict__ out, long n) {
    long idx = ((long)blockIdx.x * blockDim.x + threadIdx.x) * 4;
    if (idx + 4 <= n) {
        float4 v = *(const float4*)(in + idx);
        ushort_t o[4] = {f2bf(v.x), f2bf(v.y), f2bf(v.z), f2bf(v.w)};
        *(uint2*)(out + idx) = *(const uint2*)o;
    } else {
        for (; idx < n; ++idx) out[idx] = f2bf(in[idx]);
    }
}

// in: [z][K][N] fp32 -> out: [z][N][K] bf16.
__global__ __launch_bounds__(256) void transpose_cast(const float* __restrict__ in,
                                                      ushort_t* __restrict__ out,
                                                      int K, int N) {
    __shared__ float tile[32][33];
    const float* inp = in + (size_t)blockIdx.z * K * N;
    ushort_t* outp = out + (size_t)blockIdx.z * K * N;
    int n0 = blockIdx.x * 32, k0 = blockIdx.y * 32;
    int tx = threadIdx.x & 31, ty = threadIdx.x >> 5;
#pragma unroll
    for (int s = 0; s < 4; ++s)
        tile[ty + 8 * s][tx] = inp[(size_t)(k0 + ty + 8 * s) * N + n0 + tx];
    __syncthreads();
#pragma unroll
    for (int s = 0; s < 4; ++s)
        outp[(size_t)(n0 + ty + 8 * s) * K + k0 + tx] = f2bf(tile[tx][ty + 8 * s]);
}

// ---------------- persistent spliced 256x256 8-phase MFMA GEMM -------------------
// Verified 8-phase core (T2 swizzle + T3/T4 counted vmcnt + T5 setprio).
// ZERO-DRAIN SPLICE: the last two windows of each tile (whose stage-guard slots
// were idle) stage the NEXT tile's 7 prologue half-tiles into the exact same
// buffer slots, branch-free (peeled windows WS0/WS1, not per-stage branches —
// round-3's regression). vmcnt FIFO invariant desk-checked: WS1-ph4's vmcnt(6)
// leaves exactly {A'(1,0),B'(1,0),B'(1,1)} outstanding = the steady-state
// precondition of the next tile's window 0. Pipeline never drains until the
// final tile. Epilogue (separate 16 KB c2) uses raw barriers + lgkmcnt only.

#define STAGE_A(b, h, ktx) stage_half(A, bm + (h) * 128, M, K, ((ktx) << 6), &sh.st[(b)][0][(h)][0], w, l)
#define STAGE_B(b, h, ktx) stage_half(Bt, bn + (h) * 128, N, K, ((ktx) << 6), &sh.st[(b)][1][(h)][0], w, l)

#define LOAD_A(b, qm)                                                          \
    {                                                                          \
        const ushort_t* pa_ = &sh.st[(b)][0][(qm)][0];                         \
        _Pragma("unroll") for (int i_ = 0; i_ < 4; ++i_) {                     \
            const int r_ = wm * 64 + i_ * 16 + l16;                            \
            _Pragma("unroll") for (int kk_ = 0; kk_ < 2; ++kk_) {              \
                const int ch_ = (kk_ * 4 + quad) ^ (r_ & 7);                   \
                areg[i_][kk_] = *(const short8*)&pa_[r_ * 64 + ch_ * 8];       \
            }                                                                  \
        }                                                                      \
    }

#define LOAD_B(b, qn)                                                          \
    {                                                                          \
        const ushort_t* pb_ = &sh.st[(b)][1][(qn)][0];                         \
        _Pragma("unroll") for (int j_ = 0; j_ < 2; ++j_) {                     \
            const int r_ = wn * 32 + j_ * 16 + l16;                            \
            _Pragma("unroll") for (int kk_ = 0; kk_ < 2; ++kk_) {              \
                const int ch_ = (kk_ * 4 + quad) ^ (r_ & 7);                   \
                breg[(qn)][j_][kk_] = *(const short8*)&pb_[r_ * 64 + ch_ * 8]; \
            }                                                                  \
        }                                                                      \
    }

#define MFMA_Q(qm, qn)                                                              \
    _Pragma("unroll") for (int i_ = 0; i_ < 4; ++i_)                                \
        _Pragma("unroll") for (int j_ = 0; j_ < 2; ++j_)                            \
            _Pragma("unroll") for (int kk_ = 0; kk_ < 2; ++kk_)                     \
                acc[(qm)][(qn)][i_][j_] = __builtin_amdgcn_mfma_f32_16x16x32_bf16(  \
                    areg[i_][kk_], breg[(qn)][j_][kk_], acc[(qm)][(qn)][i_][j_], 0, 0, 0);

#define PHASE_SYNC()                                                           \
    __builtin_amdgcn_s_barrier();                                              \
    asm volatile("s_waitcnt lgkmcnt(0)" ::: "memory");                         \
    __builtin_amdgcn_sched_barrier(0)

#define MFMA_PHASE(qm, qn)                                                     \
    PHASE_SYNC();                                                              \
    __builtin_amdgcn_s_setprio(1);                                             \
    MFMA_Q(qm, qn);                                                            \
    __builtin_amdgcn_s_setprio(0);                                             \
    __builtin_amdgcn_s_barrier()

// steady-state window (kt+2 < nkt always holds in the peeled loop range)
#define WINDOW(kt, b)                                                          \
    {                                                                          \
        LOAD_A(b, 0);                                                          \
        LOAD_B(b, 0);                                                          \
        STAGE_A((b) ^ 1, 1, (kt) + 1);                                         \
        MFMA_PHASE(0, 0);                                                      \
        LOAD_B(b, 1);                                                          \
        STAGE_A(b, 0, (kt) + 2);                                               \
        MFMA_PHASE(0, 1);                                                      \
        LOAD_A(b, 1);                                                          \
        STAGE_B(b, 0, (kt) + 2);                                               \
        MFMA_PHASE(1, 0);                                                      \
        STAGE_B(b, 1, (kt) + 2);                                               \
        asm volatile("s_waitcnt vmcnt(6)" ::: "memory");                       \
        __builtin_amdgcn_s_barrier();                                          \
        __builtin_amdgcn_sched_barrier(0);                                     \
        __builtin_amdgcn_s_setprio(1);                                         \
        MFMA_Q(1, 1);                                                          \
        __builtin_amdgcn_s_setprio(0);                                         \
        __builtin_amdgcn_s_barrier();                                          \
    }

// splice window nkt-2 (buf0): ph1 stages current-tile A(1,1); ph2-4 stage
// next tile's A'(0,0,k0), B'(0,0,k0), B'(0,1,k0) into the identical slots.
#define WINDOW_S0()                                                            \
    {                                                                          \
        LOAD_A(0, 0);                                                          \
        LOAD_B(0, 0);                                                          \
        STAGE_A(1, 1, nkt - 1);                                                \
        MFMA_PHASE(0, 0);                                                      \
        LOAD_B(0, 1);                                                          \
        stage_half(A, bm2, M, K, 0, &sh.st[0][0][0][0], w, l);                 \
        MFMA_PHASE(0, 1);                                                      \
        LOAD_A(0, 1);                                                          \
        stage_half(Bt, bn2, N, K, 0, &sh.st[0][1][0][0], w, l);                \
        MFMA_PHASE(1, 0);                                                      \
        stage_half(Bt, bn2 + 128, N, K, 0, &sh.st[0][1][1][0], w, l);          \
        asm volatile("s_waitcnt vmcnt(6)" ::: "memory");                       \
        __builtin_amdgcn_s_barrier();                                          \
        __builtin_amdgcn_sched_barrier(0);                                     \
        __builtin_amdgcn_s_setprio(1);                                         \
        MFMA_Q(1, 1);                                                          \
        __builtin_amdgcn_s_setprio(0);                                         \
        __builtin_amdgcn_s_barrier();                                          \
    }

// splice window nkt-1 (buf1): all four stage slots carry next-tile half-tiles
// A'(0,1,k0), A'(1,0,k1), B'(1,0,k1), B'(1,1,k1).
#define WINDOW_S1()                                                            \
    {                                                                          \
        LOAD_A(1, 0);                                                          \
        LOAD_B(1, 0);                                                          \
        stage_half(A, bm2 + 128, M, K, 0, &sh.st[0][0][1][0], w, l);           \
        MFMA_PHASE(0, 0);                                                      \
        LOAD_B(1, 1);                                                          \
        stage_half(A, bm2, M, K, 64, &sh.st[1][0][0][0], w, l);                \
        MFMA_PHASE(0, 1);                                                      \
        LOAD_A(1, 1);                                                          \
        stage_half(Bt, bn2, N, K, 64, &sh.st[1][1][0][0], w, l);               \
        MFMA_PHASE(1, 0);                                                      \
        stage_half(Bt, bn2 + 128, N, K, 64, &sh.st[1][1][1][0], w, l);         \
        asm volatile("s_waitcnt vmcnt(6)" ::: "memory");                       \
        __builtin_amdgcn_s_barrier();                                          \
        __builtin_amdgcn_sched_barrier(0);                                     \
        __builtin_amdgcn_s_setprio(1);                                         \
        MFMA_Q(1, 1);                                                          \
        __builtin_amdgcn_s_setprio(0);                                         \
        __builtin_amdgcn_s_barrier();                                          \
    }

__global__ __launch_bounds__(512, 2) void gemm256s(const ushort_t* __restrict__ A,
                                                   const ushort_t* __restrict__ Bt,
                                                   ushort_t* __restrict__ C,
                                                   int M, int K, int N,
                                                   int ntiles, int nx) {
    __shared__ struct {
        __align__(16) ushort_t st[2][2][2][128 * 64];  // [buf][A/B][half] 128 KB
        __align__(16) ushort_t c2[32 * 256];           // epilogue staging 16 KB
    } sh;

    const int t = threadIdx.x;
    const int l = t & 63;
    const int w = t >> 6;
    const int wm = w >> 2, wn = w & 3;
    const int quad = l >> 4, l16 = l & 15;

    const int nkt = K >> 6;  // >= 4 and even for all shapes here (20, 8)
    const int q8 = ntiles >> 3, r8 = ntiles & 7;

    int T = blockIdx.x;
    if (T >= ntiles) return;
    int bm, bn, bm2, bn2;
    {
        const int xcd = T & 7;
        const int wgid = ((xcd < r8) ? xcd * (q8 + 1) : r8 * (q8 + 1) + (xcd - r8) * q8) + (T >> 3);
        bm = (wgid / nx) * 256;
        bn = (wgid % nx) * 256;
    }
    int Tn = T + gridDim.x;
    bool have_next = Tn < ntiles;
    if (have_next) {
        const int xcd = Tn & 7;
        const int wgid = ((xcd < r8) ? xcd * (q8 + 1) : r8 * (q8 + 1) + (xcd - r8) * q8) + (Tn >> 3);
        bm2 = (wgid / nx) * 256;
        bn2 = (wgid % nx) * 256;
    } else {
        bm2 = bm; bn2 = bn;  // harmless dummy targets for the last tile's splice
    }

    floatx4 acc[2][2][4][2];
    short8 areg[4][2];
    short8 breg[2][2][2];

    // prologue: tile0 fully, tile1 all but Ah1; vmcnt(6) retires exactly tile0
    STAGE_A(0, 0, 0); STAGE_B(0, 0, 0); STAGE_B(0, 1, 0); STAGE_A(0, 1, 0);
    STAGE_A(1, 0, 1); STAGE_B(1, 0, 1); STAGE_B(1, 1, 1);
    asm volatile("s_waitcnt vmcnt(6)" ::: "memory");
    __builtin_amdgcn_s_barrier();

    while (true) {
#pragma unroll
        for (int a = 0; a < 2; ++a)
#pragma unroll
            for (int bq = 0; bq < 2; ++bq)
#pragma unroll
                for (int i = 0; i < 4; ++i)
#pragma unroll
                    for (int j = 0; j < 2; ++j) acc[a][bq][i][j] = (floatx4)(0.f);

        for (int kt = 0; kt + 3 < nkt; kt += 2) {
            WINDOW(kt, 0);
            WINDOW(kt + 1, 1);
        }
        WINDOW_S0();   // window nkt-2: finishes tile, stages next A'00/B'00/B'01
        WINDOW_S1();   // window nkt-1: stages next A'01/A'10/B'10/B'11
        // 6 loads of next tile remain in flight; never drained.

        // ---- epilogue: 8 passes of 32 rows via c2; raw barriers + lgkm only ----
#pragma unroll
        for (int pc = 0; pc < 8; ++pc) {
            const int qm = pc >> 2;
            const int wmSel = (pc >> 1) & 1;
            const int ih = pc & 1;
            if (wm == wmSel) {
#pragma unroll
                for (int qn = 0; qn < 2; ++qn)
#pragma unroll
                    for (int io = 0; io < 2; ++io)
#pragma unroll
                        for (int j = 0; j < 2; ++j) {
                            const int cl = qn * 128 + wn * 32 + j * 16 + l16;
                            const int i = ih * 2 + io;
#pragma unroll
                            for (int rg = 0; rg < 4; ++rg)
                                sh.c2[(io * 16 + quad * 4 + rg) * 256 + cl] =
                                    f2bf(acc[qm][qn][i][j][rg]);
                        }
            }
            asm volatile("s_waitcnt lgkmcnt(0)" ::: "memory");
            __builtin_amdgcn_s_barrier();
#pragma unroll
            for (int it = 0; it < 2; ++it) {
                const int idx = it * 512 + t;
                const int rl = idx >> 5;
                const int ch8 = (idx & 31) * 8;
                const int grow = bm + pc * 32 + rl;
                if (grow < M)
                    *(uint4*)(C + (size_t)grow * N + bn + ch8) =
                        *(const uint4*)&sh.c2[rl * 256 + ch8];
            }
            __builtin_amdgcn_s_barrier();
        }

        if (!have_next) {
            asm volatile("s_waitcnt vmcnt(0)" ::: "memory");  // drain dummy splice
            break;
        }
        T = Tn; bm = bm2; bn = bn2;
        Tn += gridDim.x;
        have_next = Tn < ntiles;
        if (have_next) {
            const int xcd = Tn & 7;
            const int wgid = ((xcd < r8) ? xcd * (q8 + 1) : r8 * (q8 + 1) + (xcd - r8) * q8) + (Tn >> 3);
            bm2 = (wgid / nx) * 256;
            bn2 = (wgid % nx) * 256;
        } else {
            bm2 = bm; bn2 = bn;
        }
        // next K-loop's window 0 reads half-tiles retired at WINDOW_S1's vmcnt(6)
    }
}

#undef STAGE_A
#undef STAGE_B
#undef LOAD_A
#undef LOAD_B
#undef MFMA_Q
#undef PHASE_SYNC
#undef MFMA_PHASE
#undef WINDOW
#undef WINDOW_S0
#undef WINDOW_S1

// ---------------- wave-per-dst segmented mean + root + bias (+relu/cast) ---------
// (round-4 version — best measured). One 64-lane wave per dst node; lane owns
// DIM/64 cols; batch-8 gather keeps 8 independent loads in flight per lane.

template <int DIM, bool L1MODE>
__global__ __launch_bounds__(64) void segsum_wave(const ushort_t* __restrict__ H,
                                                  const float* __restrict__ bias,
                                                  const int* __restrict__ off,
                                                  const int* __restrict__ cnt,
                                                  const uint2* __restrict__ edesc,
                                                  ushort_t* __restrict__ outb,
                                                  float* __restrict__ outf) {
    constexpr int VPT = DIM / 64;   // cols per lane: 8 (L1) or 4 (L2)
    constexpr int WPT = VPT / 2;    // uints per lane: 4 or 2
    const int d = blockIdx.x;
    const int t = threadIdx.x;
    const int hs = (N_REL + 1) * DIM;

    const int base = off[d * N_REL];
    const int total = off[d * N_REL + N_REL - 1] + cnt[d * N_REL + N_REL - 1] - base;

    // root + bias
    float acc[VPT];
    {
        uint_t rw[WPT];
        const ushort_t* hp = H + (size_t)d * hs + VPT * t;
        if constexpr (WPT == 4) *(uint4*)rw = *(const uint4*)hp;
        else                    *(uint2*)rw = *(const uint2*)hp;
#pragma unroll
        for (int jq = 0; jq < WPT; ++jq) {
            acc[2 * jq]     = __uint_as_float(rw[jq] << 16);
            acc[2 * jq + 1] = __uint_as_float(rw[jq] & 0xffff0000u);
        }
        const float* bp = bias + VPT * t;
#pragma unroll
        for (int jq = 0; jq < VPT; ++jq) acc[jq] += bp[jq];
    }

    const uint2* __restrict__ ed = edesc + base;
    const ushort_t* __restrict__ Hlane = H + VPT * t;

    int p = 0;
    while (p + 8 <= total) {
        uint2 dsc[8];
#pragma unroll
        for (int q = 0; q < 8; ++q) dsc[q] = ed[p + q];
        uint_t val[8][WPT];
#pragma unroll
        for (int q = 0; q < 8; ++q) {
            const uint_t pk = dsc[q].x;
            const size_t s = pk & 0x07ffffffu;
            const int r = pk >> 27;
            const ushort_t* hp = Hlane + s * hs + (r + 1) * DIM;
            if constexpr (WPT == 4) *(uint4*)val[q] = *(const uint4*)hp;
            else                    *(uint2*)val[q] = *(const uint2*)hp;
        }
#pragma unroll
        for (int q = 0; q < 8; ++q) {
            const float inv = __uint_as_float(dsc[q].y);
#pragma unroll
            for (int jq = 0; jq < WPT; ++jq) {
                acc[2 * jq]     += inv * __uint_as_float(val[q][jq] << 16);
                acc[2 * jq + 1] += inv * __uint_as_float(val[q][jq] & 0xffff0000u);
            }
        }
        p += 8;
    }
    for (; p < total; ++p) {
        const uint2 dq = ed[p];
        const uint_t pk = dq.x;
        const size_t s = pk & 0x07ffffffu;
        const int r = pk >> 27;
        const float inv = __uint_as_float(dq.y);
        uint_t vw[WPT];
        const ushort_t* hp = Hlane + s * hs + (r + 1) * DIM;
        if constexpr (WPT == 4) *(uint4*)vw = *(const uint4*)hp;
        else                    *(uint2*)vw = *(const uint2*)hp;
#pragma unroll
        for (int jq = 0; jq < WPT; ++jq) {
            acc[2 * jq]     += inv * __uint_as_float(vw[jq] << 16);
            acc[2 * jq + 1] += inv * __uint_as_float(vw[jq] & 0xffff0000u);
        }
    }

    if constexpr (L1MODE) {
        ushort_t ob[VPT];
#pragma unroll
        for (int jq = 0; jq < VPT; ++jq) ob[jq] = f2bf(fmaxf(acc[jq], 0.f));
        if constexpr (WPT == 4)
            *(uint4*)(outb + (size_t)d * DIM + VPT * t) = *(const uint4*)ob;
        else
            *(uint2*)(outb + (size_t)d * DIM + VPT * t) = *(const uint2*)ob;
    } else {
        float* op = outf + (size_t)d * DIM + VPT * t;
#pragma unroll
        for (int jq = 0; jq < WPT; ++jq)
            *(float2*)(op + 2 * jq) = make_float2(acc[2 * jq], acc[2 * jq + 1]);
    }
}

// ---------------- launcher ----------------

extern "C" void kernel_launch(void* const* d_in, const int* in_sizes, int n_in,
                              void* d_out, int out_size, void* d_ws, size_t ws_size,
                              hipStream_t stream) {
    const float* x     = (const float*)d_in[0];
    const int*   eidx  = (const int*)d_in[1];
    const int*   etype = (const int*)d_in[2];
    const float* W1    = (const float*)d_in[3];
    const float* root1 = (const float*)d_in[4];
    const float* b1    = (const float*)d_in[5];
    const float* W2    = (const float*)d_in[6];
    const float* root2 = (const float*)d_in[7];
    const float* b2    = (const float*)d_in[8];
    float* out = (float*)d_out;

    const int IN_DIM = 1280, HID_DIM = 512, OUT_DIM = 256;
    const int E = in_sizes[2];
    const int N = in_sizes[0] / IN_DIM;
    const int NK = N * N_REL;
    const int* srcs = eidx;
    const int* dsts = eidx + E;

    char* ws = (char*)d_ws;
    size_t offb = 0;
    auto alloc = [&](size_t bytes) { void* p = ws + offb; offb += (bytes + 255) & ~(size_t)255; return p; };
    int*      cnt    = (int*)alloc((size_t)NK * 4);
    int*      off    = (int*)alloc((size_t)NK * 4);
    int*      cursor = (int*)alloc((size_t)NK * 4);
    int*      bsum   = (int*)alloc(1024 * 4);
    uint2*    edesc  = (uint2*)alloc((size_t)E * 8);
    ushort_t* x_bf   = (ushort_t*)alloc((size_t)N * IN_DIM * 2);   // reused as hb_bf later
    ushort_t* rW1t   = (ushort_t*)alloc((size_t)(N_REL + 1) * IN_DIM * HID_DIM * 2);
    ushort_t* r1t    = rW1t;
    ushort_t* W1t    = rW1t + (size_t)HID_DIM * IN_DIM;
    ushort_t* rW2t   = (ushort_t*)alloc((size_t)(N_REL + 1) * HID_DIM * OUT_DIM * 2);
    ushort_t* r2t    = rW2t;
    ushort_t* W2t    = rW2t + (size_t)OUT_DIM * HID_DIM;
    ushort_t* Hb     = (ushort_t*)alloc((size_t)N * (N_REL + 1) * HID_DIM * 2);  // 184 MB
    ushort_t* hb_bf  = x_bf;  // x_bf dead after layer-1 GEMM
    (void)ws_size;

    const int nb = (NK + 255) / 256;

    // 1) sort edges by (dst, rel); build per-edge descriptors {src|rel<<27, 1/c}
    hipMemsetAsync(cnt, 0, (size_t)NK * 4, stream);
    hist_kernel<<<(E + 255) / 256, 256, 0, stream>>>(dsts, etype, cnt, E);
    scan1<<<nb, 256, 0, stream>>>(cnt, off, bsum, NK);
    scan2<<<1, 1024, 0, stream>>>(bsum, nb);
    scan3<<<nb, 256, 0, stream>>>(off, bsum, cursor, NK);
    scatter_desc<<<(E + 255) / 256, 256, 0, stream>>>(dsts, etype, srcs, cnt, cursor, edesc, E);

    // 2) casts / weight transposes (into the concatenated Bt buffers)
    {
        long n = (long)N * IN_DIM;
        cast_bf16<<<(unsigned)((n / 4 + 255) / 256), 256, 0, stream>>>(x, x_bf, n);
    }
    transpose_cast<<<dim3(HID_DIM / 32, IN_DIM / 32, 1), 256, 0, stream>>>(root1, r1t, IN_DIM, HID_DIM);
    transpose_cast<<<dim3(HID_DIM / 32, IN_DIM / 32, N_REL), 256, 0, stream>>>(W1, W1t, IN_DIM, HID_DIM);
    transpose_cast<<<dim3(OUT_DIM / 32, HID_DIM / 32, 1), 256, 0, stream>>>(root2, r2t, HID_DIM, OUT_DIM);
    transpose_cast<<<dim3(OUT_DIM / 32, HID_DIM / 32, N_REL), 256, 0, stream>>>(W2, W2t, HID_DIM, OUT_DIM);

    const int mb = (N + 255) / 256;  // 79

    // 3) layer 1: spliced persistent GEMM (root + 8 relations) -> segsum+relu+cast
    {
        const int NTOT = (N_REL + 1) * HID_DIM;  // 4608
        const int nxg = NTOT / 256;              // 18
        gemm256s<<<256, 512, 0, stream>>>(x_bf, rW1t, Hb, N, IN_DIM, NTOT, mb * nxg, nxg);
        segsum_wave<512, true><<<N, 64, 0, stream>>>(Hb, b1, off, cnt, edesc, hb_bf, nullptr);
    }

    // 4) layer 2: spliced persistent GEMM -> segsum -> out
    {
        const int NTOT = (N_REL + 1) * OUT_DIM;  // 2304
        const int nxg = NTOT / 256;              // 9
        gemm256s<<<256, 512, 0, stream>>>(hb_bf, rW2t, Hb, N, HID_DIM, NTOT, mb * nxg, nxg);
        segsum_wave<256, false><<<N, 64, 0, stream>>>(Hb, b2, off, cnt, edesc, nullptr, out);
    }
}

// Round 7
// 611.252 us; speedup vs baseline: 1.3082x; 1.3082x over previous
//
#include <hip/hip_runtime.h>
#include <hip/hip_bf16.h>

#define N_REL 8

typedef unsigned short ushort_t;
typedef unsigned int uint_t;
typedef __attribute__((ext_vector_type(8))) short short8;   // bf16x8 MFMA operand
typedef __attribute__((ext_vector_type(4))) float floatx4;  // MFMA accumulator

static __device__ __forceinline__ ushort_t f2bf(float f) {
    union { float f; unsigned u; } v; v.f = f;
    unsigned r = v.u + 0x7fff + ((v.u >> 16) & 1);
    return (ushort_t)(r >> 16);
}

typedef __attribute__((address_space(1))) void glob_void;
typedef __attribute__((address_space(3))) void lds_void;

static __device__ __forceinline__ void load_lds16(const void* g, void* l) {
    __builtin_amdgcn_global_load_lds((glob_void*)g, (lds_void*)l, 16, 0, 0);
}

// Stage one 128x64 bf16 half-tile (16 KB) from global [rows][K] into LDS, linear
// [r][chunk] layout, with the st-swizzle (chunk ^= r&7) pre-applied on the GLOBAL
// source address (global_load_lds writes wave-uniform-base + lane*16 only).
static __device__ __forceinline__ void stage_half(const ushort_t* __restrict__ g,
                                                  int row0, int rmax, int K, int k0,
                                                  ushort_t* lds, int w, int l) {
    const int rl = l >> 3;
    const int gc = ((l & 7) ^ rl) * 8;  // swizzled 16B chunk within the row
#pragma unroll
    for (int s = 0; s < 2; ++s) {
        int r = row0 + s * 64 + w * 8 + rl;
        r = r < rmax ? r : rmax - 1;  // clamp (stores are guarded; dup rows harmless)
        load_lds16(g + (size_t)r * K + k0 + gc, lds + (s * 64 + w * 8) * 64);
    }
}

// ---------------- sort infrastructure ----------------

__global__ __launch_bounds__(256) void hist_kernel(const int* __restrict__ dst,
                                                   const int* __restrict__ et,
                                                   int* __restrict__ cnt, int E) {
    int e = blockIdx.x * blockDim.x + threadIdx.x;
    if (e < E) atomicAdd(&cnt[dst[e] * N_REL + et[e]], 1);
}

__global__ __launch_bounds__(256) void scan1(const int* __restrict__ cnt,
                                             int* __restrict__ off,
                                             int* __restrict__ bsum, int nk) {
    __shared__ int s[256];
    int t = threadIdx.x;
    int k = blockIdx.x * 256 + t;
    int v = k < nk ? cnt[k] : 0;
    s[t] = v; __syncthreads();
    for (int d = 1; d < 256; d <<= 1) {
        int x = (t >= d) ? s[t - d] : 0;
        __syncthreads(); s[t] += x; __syncthreads();
    }
    if (k < nk) off[k] = s[t] - v;
    if (t == 255) bsum[blockIdx.x] = s[255];
}

__global__ __launch_bounds__(1024) void scan2(int* __restrict__ bsum, int nb) {
    __shared__ int s[1024];
    int t = threadIdx.x;
    int v = t < nb ? bsum[t] : 0;
    s[t] = v; __syncthreads();
    for (int d = 1; d < 1024; d <<= 1) {
        int x = (t >= d) ? s[t - d] : 0;
        __syncthreads(); s[t] += x; __syncthreads();
    }
    if (t < nb) bsum[t] = s[t] - v;
}

__global__ __launch_bounds__(256) void scan3(int* __restrict__ off,
                                             const int* __restrict__ bsum,
                                             int* __restrict__ cursor,
                                             int nk) {
    int k = blockIdx.x * 256 + threadIdx.x;
    if (k >= nk) return;
    int o = off[k] + bsum[k >> 8];
    off[k] = o;
    cursor[k] = o;
}

// Packs everything the gather loop needs into one 8-byte descriptor per edge:
// {src | rel<<27, 1.0f/count}. cnt[] is final (hist completed) when this runs.
__global__ __launch_bounds__(256) void scatter_desc(const int* __restrict__ dst,
                                                    const int* __restrict__ et,
                                                    const int* __restrict__ src,
                                                    const int* __restrict__ cnt,
                                                    int* __restrict__ cursor,
                                                    uint2* __restrict__ edesc, int E) {
    int e = blockIdx.x * blockDim.x + threadIdx.x;
    if (e < E) {
        int key = dst[e] * N_REL + et[e];
        int pos = atomicAdd(&cursor[key], 1);
        float inv = 1.0f / (float)cnt[key];
        edesc[pos] = make_uint2((uint_t)src[e] | ((uint_t)et[e] << 27),
                                __float_as_uint(inv));
    }
}

// ---------------- casts ----------------

__global__ __launch_bounds__(256) void cast_bf16(const float* __restrict__ in,
                                                 ushort_t* __restrict__ out, long n) {
    long idx = ((long)blockIdx.x * blockDim.x + threadIdx.x) * 4;
    if (idx + 4 <= n) {
        float4 v = *(const float4*)(in + idx);
        ushort_t o[4] = {f2bf(v.x), f2bf(v.y), f2bf(v.z), f2bf(v.w)};
        *(uint2*)(out + idx) = *(const uint2*)o;
    } else {
        for (; idx < n; ++idx) out[idx] = f2bf(in[idx]);
    }
}

// in: [z][K][N] fp32 -> out: [z][N][K] bf16.
__global__ __launch_bounds__(256) void transpose_cast(const float* __restrict__ in,
                                                      ushort_t* __restrict__ out,
                                                      int K, int N) {
    __shared__ float tile[32][33];
    const float* inp = in + (size_t)blockIdx.z * K * N;
    ushort_t* outp = out + (size_t)blockIdx.z * K * N;
    int n0 = blockIdx.x * 32, k0 = blockIdx.y * 32;
    int tx = threadIdx.x & 31, ty = threadIdx.x >> 5;
#pragma unroll
    for (int s = 0; s < 4; ++s)
        tile[ty + 8 * s][tx] = inp[(size_t)(k0 + ty + 8 * s) * N + n0 + tx];
    __syncthreads();
#pragma unroll
    for (int s = 0; s < 4; ++s)
        outp[(size_t)(n0 + ty + 8 * s) * K + k0 + tx] = f2bf(tile[tx][ty + 8 * s]);
}

// ---------------- 256x256 8-phase MFMA GEMM: C[M,N] = A[M,K] @ Bt[N,K]^T ---------
// Verified 8-phase template (T2 st-swizzle + T3/T4 counted vmcnt + T5 setprio).
// ROUND-4 VERSION VERBATIM — best measured (259us L1). Persistence variants
// (r3: per-stage branches; r5: prologue-behind-epilogue; r6: window splice)
// measured -47/0/-130us — the counted-vmcnt schedule does not compose with
// bulk store epilogues (stores share the vmcnt FIFO; r6 post-mortem).

#define STAGE_A(b, h, ktx) stage_half(A, bm + (h) * 128, M, K, ((ktx) << 6), &sh.st[(b)][0][(h)][0], w, l)
#define STAGE_B(b, h, ktx) stage_half(Bt, bn + (h) * 128, N, K, ((ktx) << 6), &sh.st[(b)][1][(h)][0], w, l)

#define LOAD_A(b, qm)                                                          \
    {                                                                          \
        const ushort_t* pa_ = &sh.st[(b)][0][(qm)][0];                         \
        _Pragma("unroll") for (int i_ = 0; i_ < 4; ++i_) {                     \
            const int r_ = wm * 64 + i_ * 16 + l16;                            \
            _Pragma("unroll") for (int kk_ = 0; kk_ < 2; ++kk_) {              \
                const int ch_ = (kk_ * 4 + quad) ^ (r_ & 7);                   \
                areg[i_][kk_] = *(const short8*)&pa_[r_ * 64 + ch_ * 8];       \
            }                                                                  \
        }                                                                      \
    }

#define LOAD_B(b, qn)                                                          \
    {                                                                          \
        const ushort_t* pb_ = &sh.st[(b)][1][(qn)][0];                         \
        _Pragma("unroll") for (int j_ = 0; j_ < 2; ++j_) {                     \
            const int r_ = wn * 32 + j_ * 16 + l16;                            \
            _Pragma("unroll") for (int kk_ = 0; kk_ < 2; ++kk_) {              \
                const int ch_ = (kk_ * 4 + quad) ^ (r_ & 7);                   \
                breg[(qn)][j_][kk_] = *(const short8*)&pb_[r_ * 64 + ch_ * 8]; \
            }                                                                  \
        }                                                                      \
    }

#define MFMA_Q(qm, qn)                                                              \
    _Pragma("unroll") for (int i_ = 0; i_ < 4; ++i_)                                \
        _Pragma("unroll") for (int j_ = 0; j_ < 2; ++j_)                            \
            _Pragma("unroll") for (int kk_ = 0; kk_ < 2; ++kk_)                     \
                acc[(qm)][(qn)][i_][j_] = __builtin_amdgcn_mfma_f32_16x16x32_bf16(  \
                    areg[i_][kk_], breg[(qn)][j_][kk_], acc[(qm)][(qn)][i_][j_], 0, 0, 0);

#define PHASE_SYNC()                                                           \
    __builtin_amdgcn_s_barrier();                                              \
    asm volatile("s_waitcnt lgkmcnt(0)" ::: "memory");                         \
    __builtin_amdgcn_sched_barrier(0)

#define WINDOW(kt, b)                                                          \
    {                                                                          \
        /* phase 1: quadrant (0,0) — reads Ah0, Bh0 */                         \
        LOAD_A(b, 0);                                                          \
        LOAD_B(b, 0);                                                          \
        if ((kt) + 1 < nkt) STAGE_A((b) ^ 1, 1, (kt) + 1);                     \
        PHASE_SYNC();                                                          \
        __builtin_amdgcn_s_setprio(1);                                         \
        MFMA_Q(0, 0);                                                          \
        __builtin_amdgcn_s_setprio(0);                                         \
        __builtin_amdgcn_s_barrier();                                          \
        /* phase 2: quadrant (0,1) — reads Bh1; Ah0 now free */                \
        LOAD_B(b, 1);                                                          \
        if ((kt) + 2 < nkt) STAGE_A(b, 0, (kt) + 2);                           \
        PHASE_SYNC();                                                          \
        __builtin_amdgcn_s_setprio(1);                                         \
        MFMA_Q(0, 1);                                                          \
        __builtin_amdgcn_s_setprio(0);                                         \
        __builtin_amdgcn_s_barrier();                                          \
        /* phase 3: quadrant (1,0) — reads Ah1; Bh0 free */                    \
        LOAD_A(b, 1);                                                          \
        if ((kt) + 2 < nkt) STAGE_B(b, 0, (kt) + 2);                           \
        PHASE_SYNC();                                                          \
        __builtin_amdgcn_s_setprio(1);                                         \
        MFMA_Q(1, 0);                                                          \
        __builtin_amdgcn_s_setprio(0);                                         \
        __builtin_amdgcn_s_barrier();                                          \
        /* phase 4: quadrant (1,1) — no ds_reads; Bh1 free; counted vmcnt */   \
        if ((kt) + 2 < nkt) {                                                  \
            STAGE_B(b, 1, (kt) + 2);                                           \
            asm volatile("s_waitcnt vmcnt(6)" ::: "memory");                   \
        } else {                                                               \
            asm volatile("s_waitcnt vmcnt(0)" ::: "memory"); /* epilogue drain */ \
        }                                                                      \
        __builtin_amdgcn_s_barrier();                                          \
        __builtin_amdgcn_sched_barrier(0);                                     \
        __builtin_amdgcn_s_setprio(1);                                         \
        MFMA_Q(1, 1);                                                          \
        __builtin_amdgcn_s_setprio(0);                                         \
        __builtin_amdgcn_s_barrier();                                          \
    }

__global__ __launch_bounds__(512, 2) void gemm256(const ushort_t* __restrict__ A,
                                                  const ushort_t* __restrict__ Bt,
                                                  ushort_t* __restrict__ C,
                                                  int M, int K, int N) {
    __shared__ union {
        __align__(16) ushort_t st[2][2][2][128 * 64];  // [buf][A/B][half][r*64+c]
        __align__(16) ushort_t c[256 * 256];           // bf16 epilogue staging (128 KB)
    } sh;

    const int t = threadIdx.x;
    const int l = t & 63;
    const int w = t >> 6;
    const int wm = w >> 2, wn = w & 3;
    const int quad = l >> 4, l16 = l & 15;

    // bijective XCD-aware swizzle (m204): consecutive wgids land on one XCD
    const int nx = gridDim.x;
    const int nwg = nx * gridDim.y;
    const int orig = blockIdx.y * nx + blockIdx.x;
    const int q8 = nwg >> 3, r8 = nwg & 7;
    const int xcd = orig & 7;
    const int wgid = ((xcd < r8) ? xcd * (q8 + 1) : r8 * (q8 + 1) + (xcd - r8) * q8) + (orig >> 3);
    const int bm = (wgid / nx) * 256;
    const int bn = (wgid % nx) * 256;

    const int nkt = K >> 6;  // K-tiles of 64; K % 128 == 0 for all our shapes

    floatx4 acc[2][2][4][2];
#pragma unroll
    for (int a = 0; a < 2; ++a)
#pragma unroll
        for (int bq = 0; bq < 2; ++bq)
#pragma unroll
            for (int i = 0; i < 4; ++i)
#pragma unroll
                for (int j = 0; j < 2; ++j) acc[a][bq][i][j] = (floatx4)(0.f);

    short8 areg[4][2];
    short8 breg[2][2][2];

    // prologue: tile0 fully, tile1 all but Ah1; vmcnt(6) retires exactly tile0
    STAGE_A(0, 0, 0); STAGE_B(0, 0, 0); STAGE_B(0, 1, 0); STAGE_A(0, 1, 0);
    STAGE_A(1, 0, 1); STAGE_B(1, 0, 1); STAGE_B(1, 1, 1);
    asm volatile("s_waitcnt vmcnt(6)" ::: "memory");
    __builtin_amdgcn_s_barrier();

    for (int kt = 0; kt < nkt; kt += 2) {
        WINDOW(kt, 0);
        WINDOW(kt + 1, 1);
    }

    __syncthreads();  // union transition: all LDS reads done before C staging
#pragma unroll
    for (int qm = 0; qm < 2; ++qm)
#pragma unroll
        for (int qn = 0; qn < 2; ++qn)
#pragma unroll
            for (int i = 0; i < 4; ++i)
#pragma unroll
                for (int j = 0; j < 2; ++j) {
                    const int rl = qm * 128 + wm * 64 + i * 16 + quad * 4;
                    const int cl = qn * 128 + wn * 32 + j * 16 + l16;
#pragma unroll
                    for (int rg = 0; rg < 4; ++rg)
                        sh.c[(rl + rg) * 256 + cl] = f2bf(acc[qm][qn][i][j][rg]);
                }
    __syncthreads();
#pragma unroll
    for (int sw = 0; sw < 16; ++sw) {
        const int idx = sw * 512 + t;
        const int row = idx >> 5;
        const int ch = (idx & 31) * 8;
        const int grow = bm + row;
        if (grow < M)
            *(uint4*)(C + (size_t)grow * N + bn + ch) = *(const uint4*)&sh.c[row * 256 + ch];
    }
}

#undef STAGE_A
#undef STAGE_B
#undef LOAD_A
#undef LOAD_B
#undef MFMA_Q
#undef PHASE_SYNC
#undef WINDOW

// ---------------- 2-wave edge-split segmented mean + root + bias (+relu/cast) ----
// 128 threads (2 waves) per dst node. Each wave covers the FULL dim (VPT cols
// per lane) but only HALF the edge list — wave0 [0,h), wave1 [h,total), h
// 8-aligned. Doubles loads-in-flight per dst AND resident waves per CU vs the
// 64-thread version (which was workgroup-slot capped at ~25% occupancy).
// Batch-8 gather, static indexing; LDS merge (DIM floats); wave0 adds root+bias.

template <int DIM, bool L1MODE>
__global__ __launch_bounds__(128) void segsum_wave2(const ushort_t* __restrict__ H,
                                                    const float* __restrict__ bias,
                                                    const int* __restrict__ off,
                                                    const int* __restrict__ cnt,
                                                    const uint2* __restrict__ edesc,
                                                    ushort_t* __restrict__ outb,
                                                    float* __restrict__ outf) {
    constexpr int VPT = DIM / 64;   // cols per lane: 8 (L1) or 4 (L2)
    constexpr int WPT = VPT / 2;    // uints per lane: 4 or 2
    const int d = blockIdx.x;
    const int lane = threadIdx.x & 63;
    const int wv = threadIdx.x >> 6;
    const int hs = (N_REL + 1) * DIM;
    __shared__ float red[DIM];

    const int base = off[d * N_REL];
    const int total = off[d * N_REL + N_REL - 1] + cnt[d * N_REL + N_REL - 1] - base;
    int h = ((total >> 1) + 7) & ~7;  // wave0 edge share, 8-aligned
    if (h > total) h = total;
    const int start = wv ? h : 0;
    const int end = wv ? total : h;

    float acc[VPT];
    if (wv == 0) {
        // root + bias
        uint_t rw[WPT];
        const ushort_t* hp = H + (size_t)d * hs + VPT * lane;
        if constexpr (WPT == 4) *(uint4*)rw = *(const uint4*)hp;
        else                    *(uint2*)rw = *(const uint2*)hp;
#pragma unroll
        for (int jq = 0; jq < WPT; ++jq) {
            acc[2 * jq]     = __uint_as_float(rw[jq] << 16);
            acc[2 * jq + 1] = __uint_as_float(rw[jq] & 0xffff0000u);
        }
        const float* bp = bias + VPT * lane;
#pragma unroll
        for (int jq = 0; jq < VPT; ++jq) acc[jq] += bp[jq];
    } else {
#pragma unroll
        for (int jq = 0; jq < VPT; ++jq) acc[jq] = 0.f;
    }

    const uint2* __restrict__ ed = edesc + base;
    const ushort_t* __restrict__ Hlane = H + VPT * lane;

    int p = start;
    while (p + 8 <= end) {
        uint2 dsc[8];
#pragma unroll
        for (int q = 0; q < 8; ++q) dsc[q] = ed[p + q];
        uint_t val[8][WPT];
#pragma unroll
        for (int q = 0; q < 8; ++q) {
            const uint_t pk = dsc[q].x;
            const size_t s = pk & 0x07ffffffu;
            const int r = pk >> 27;
            const ushort_t* hp = Hlane + s * hs + (r + 1) * DIM;
            if constexpr (WPT == 4) *(uint4*)val[q] = *(const uint4*)hp;
            else                    *(uint2*)val[q] = *(const uint2*)hp;
        }
#pragma unroll
        for (int q = 0; q < 8; ++q) {
            const float inv = __uint_as_float(dsc[q].y);
#pragma unroll
            for (int jq = 0; jq < WPT; ++jq) {
                acc[2 * jq]     += inv * __uint_as_float(val[q][jq] << 16);
                acc[2 * jq + 1] += inv * __uint_as_float(val[q][jq] & 0xffff0000u);
            }
        }
        p += 8;
    }
    for (; p < end; ++p) {
        const uint2 dq = ed[p];
        const uint_t pk = dq.x;
        const size_t s = pk & 0x07ffffffu;
        const int r = pk >> 27;
        const float inv = __uint_as_float(dq.y);
        uint_t vw[WPT];
        const ushort_t* hp = Hlane + s * hs + (r + 1) * DIM;
        if constexpr (WPT == 4) *(uint4*)vw = *(const uint4*)hp;
        else                    *(uint2*)vw = *(const uint2*)hp;
#pragma unroll
        for (int jq = 0; jq < WPT; ++jq) {
            acc[2 * jq]     += inv * __uint_as_float(vw[jq] << 16);
            acc[2 * jq + 1] += inv * __uint_as_float(vw[jq] & 0xffff0000u);
        }
    }

    // merge wave1 into wave0 via LDS
    if (wv == 1) {
#pragma unroll
        for (int jq = 0; jq < VPT; ++jq) red[VPT * lane + jq] = acc[jq];
    }
    __syncthreads();
    if (wv == 0) {
#pragma unroll
        for (int jq = 0; jq < VPT; ++jq) acc[jq] += red[VPT * lane + jq];

        if constexpr (L1MODE) {
            ushort_t ob[VPT];
#pragma unroll
            for (int jq = 0; jq < VPT; ++jq) ob[jq] = f2bf(fmaxf(acc[jq], 0.f));
            if constexpr (WPT == 4)
                *(uint4*)(outb + (size_t)d * DIM + VPT * lane) = *(const uint4*)ob;
            else
                *(uint2*)(outb + (size_t)d * DIM + VPT * lane) = *(const uint2*)ob;
        } else {
            float* op = outf + (size_t)d * DIM + VPT * lane;
#pragma unroll
            for (int jq = 0; jq < WPT; ++jq)
                *(float2*)(op + 2 * jq) = make_float2(acc[2 * jq], acc[2 * jq + 1]);
        }
    }
}

// ---------------- launcher ----------------

extern "C" void kernel_launch(void* const* d_in, const int* in_sizes, int n_in,
                              void* d_out, int out_size, void* d_ws, size_t ws_size,
                              hipStream_t stream) {
    const float* x     = (const float*)d_in[0];
    const int*   eidx  = (const int*)d_in[1];
    const int*   etype = (const int*)d_in[2];
    const float* W1    = (const float*)d_in[3];
    const float* root1 = (const float*)d_in[4];
    const float* b1    = (const float*)d_in[5];
    const float* W2    = (const float*)d_in[6];
    const float* root2 = (const float*)d_in[7];
    const float* b2    = (const float*)d_in[8];
    float* out = (float*)d_out;

    const int IN_DIM = 1280, HID_DIM = 512, OUT_DIM = 256;
    const int E = in_sizes[2];
    const int N = in_sizes[0] / IN_DIM;
    const int NK = N * N_REL;
    const int* srcs = eidx;
    const int* dsts = eidx + E;

    char* ws = (char*)d_ws;
    size_t offb = 0;
    auto alloc = [&](size_t bytes) { void* p = ws + offb; offb += (bytes + 255) & ~(size_t)255; return p; };
    int*      cnt    = (int*)alloc((size_t)NK * 4);
    int*      off    = (int*)alloc((size_t)NK * 4);
    int*      cursor = (int*)alloc((size_t)NK * 4);
    int*      bsum   = (int*)alloc(1024 * 4);
    uint2*    edesc  = (uint2*)alloc((size_t)E * 8);
    ushort_t* x_bf   = (ushort_t*)alloc((size_t)N * IN_DIM * 2);   // reused as hb_bf later
    ushort_t* rW1t   = (ushort_t*)alloc((size_t)(N_REL + 1) * IN_DIM * HID_DIM * 2);
    ushort_t* r1t    = rW1t;
    ushort_t* W1t    = rW1t + (size_t)HID_DIM * IN_DIM;
    ushort_t* rW2t   = (ushort_t*)alloc((size_t)(N_REL + 1) * HID_DIM * OUT_DIM * 2);
    ushort_t* r2t    = rW2t;
    ushort_t* W2t    = rW2t + (size_t)OUT_DIM * HID_DIM;
    ushort_t* Hb     = (ushort_t*)alloc((size_t)N * (N_REL + 1) * HID_DIM * 2);  // 184 MB
    ushort_t* hb_bf  = x_bf;  // x_bf dead after layer-1 GEMM
    (void)ws_size;

    const int nb = (NK + 255) / 256;

    // 1) sort edges by (dst, rel); build per-edge descriptors {src|rel<<27, 1/c}
    hipMemsetAsync(cnt, 0, (size_t)NK * 4, stream);
    hist_kernel<<<(E + 255) / 256, 256, 0, stream>>>(dsts, etype, cnt, E);
    scan1<<<nb, 256, 0, stream>>>(cnt, off, bsum, NK);
    scan2<<<1, 1024, 0, stream>>>(bsum, nb);
    scan3<<<nb, 256, 0, stream>>>(off, bsum, cursor, NK);
    scatter_desc<<<(E + 255) / 256, 256, 0, stream>>>(dsts, etype, srcs, cnt, cursor, edesc, E);

    // 2) casts / weight transposes (into the concatenated Bt buffers)
    {
        long n = (long)N * IN_DIM;
        cast_bf16<<<(unsigned)((n / 4 + 255) / 256), 256, 0, stream>>>(x, x_bf, n);
    }
    transpose_cast<<<dim3(HID_DIM / 32, IN_DIM / 32, 1), 256, 0, stream>>>(root1, r1t, IN_DIM, HID_DIM);
    transpose_cast<<<dim3(HID_DIM / 32, IN_DIM / 32, N_REL), 256, 0, stream>>>(W1, W1t, IN_DIM, HID_DIM);
    transpose_cast<<<dim3(OUT_DIM / 32, HID_DIM / 32, 1), 256, 0, stream>>>(root2, r2t, HID_DIM, OUT_DIM);
    transpose_cast<<<dim3(OUT_DIM / 32, HID_DIM / 32, N_REL), 256, 0, stream>>>(W2, W2t, HID_DIM, OUT_DIM);

    const int mb = (N + 255) / 256;  // 79

    // 3) layer 1: fused GEMM (root + 8 relations, N=4608) -> 2-wave segsum
    {
        const int NTOT = (N_REL + 1) * HID_DIM;  // 4608
        gemm256<<<dim3(NTOT / 256, mb), 512, 0, stream>>>(x_bf, rW1t, Hb, N, IN_DIM, NTOT);
        segsum_wave2<512, true><<<N, 128, 0, stream>>>(Hb, b1, off, cnt, edesc, hb_bf, nullptr);
    }

    // 4) layer 2: fused GEMM (root + 8 relations, N=2304) -> 2-wave segsum -> out
    {
        const int NTOT = (N_REL + 1) * OUT_DIM;  // 2304
        gemm256<<<dim3(NTOT / 256, mb), 512, 0, stream>>>(hb_bf, rW2t, Hb, N, HID_DIM, NTOT);
        segsum_wave2<256, false><<<N, 128, 0, stream>>>(Hb, b2, off, cnt, edesc, nullptr, out);
    }
}